// Round 5
// baseline (55.245 us; speedup 1.0000x reference)
//
#include <hip/hip_runtime.h>
#include <stdint.h>

// Problem constants: x (4096, 2048) int32 {0,1}, references (1024, 2048)
// float32 {0,1}, out (4096, 1024) float32.
constexpr int B_ROWS  = 4096;
constexpr int D_ROWS  = 1024;
constexpr int L_LEN   = 2048;
constexpr int L_WORDS = L_LEN / 64;   // 32 packed uint64 per row

// ---------------------------------------------------------------------------
// Kernel 1 (UNCHANGED from R2/R3 — control for timing attribution):
// bit-pack both inputs via wave64 __ballot. Bit i of word (g,k) = element
// g*256 + i*4 + k; same permutation for x and refs, so popcount(xor) is the
// exact Hamming distance.
// ---------------------------------------------------------------------------
__global__ __launch_bounds__(256) void pack_bits_kernel(
    const int* __restrict__ x, const float* __restrict__ r,
    uint64_t* __restrict__ xp, uint64_t* __restrict__ rp,
    int groups_x, int groups_total)
{
  const int lane   = threadIdx.x & 63;
  const int wave   = (int)((blockIdx.x * blockDim.x + threadIdx.x) >> 6);
  const int nwaves = (int)((gridDim.x * blockDim.x) >> 6);

  for (int g = wave; g < groups_total; g += nwaves) {
    if (g < groups_x) {
      const int4 v = *reinterpret_cast<const int4*>(x + (size_t)g * 256 + lane * 4);
      uint64_t m0 = __ballot(v.x != 0);
      uint64_t m1 = __ballot(v.y != 0);
      uint64_t m2 = __ballot(v.z != 0);
      uint64_t m3 = __ballot(v.w != 0);
      if (lane == 0) {
        uint64_t* p = xp + (size_t)g * 4;
        p[0] = m0; p[1] = m1; p[2] = m2; p[3] = m3;
      }
    } else {
      const int gr = g - groups_x;
      const float4 v = *reinterpret_cast<const float4*>(r + (size_t)gr * 256 + lane * 4);
      uint64_t m0 = __ballot(v.x != 0.0f);
      uint64_t m1 = __ballot(v.y != 0.0f);
      uint64_t m2 = __ballot(v.z != 0.0f);
      uint64_t m3 = __ballot(v.w != 0.0f);
      if (lane == 0) {
        uint64_t* p = rp + (size_t)gr * 4;
        p[0] = m0; p[1] = m1; p[2] = m2; p[3] = m3;
      }
    }
  }
}

// ---------------------------------------------------------------------------
// Kernel 2 v3: NO LDS. Packed operands total 1.25 MiB -> fully L2-resident
// (4 MiB/XCD); per learn_hip lesson #7 (m169), LDS-staging L2-fit data is
// pure overhead. Each thread computes a 4(b) x 8(d) sub-tile reading straight
// from global:
//   x reads: fixed addr across 16 lanes (broadcast) -> 4 lines/instr
//   r reads: 16-lane gather at 256 B row stride; each 64 B line covers 4
//            consecutive w2 steps (temporal reuse in L1 under unroll 4)
// No barrier, no staging pass, no 52 KB LDS occupancy cap.
// VALU floor unchanged: 2 instr (xor + bcnt-accum) per 32 bits -> 6.8 us
// chip-wide at 2048 waves.
// ---------------------------------------------------------------------------
constexpr int BM = 64;
constexpr int BN = 128;

__global__ __launch_bounds__(256) void hamming_kernel(
    const uint64_t* __restrict__ xp, const uint64_t* __restrict__ rp,
    float* __restrict__ out)
{
  const int t   = threadIdx.x;
  const int bm0 = blockIdx.x * BM;
  const int bn0 = blockIdx.y * BN;
  const int tc  = t & 15;   // d-col group
  const int tr  = t >> 4;   // b-row group

  const uint64_t* xr[4];
  const uint64_t* rr[8];
#pragma unroll
  for (int i = 0; i < 4; ++i)
    xr[i] = xp + (size_t)(bm0 + tr * 4 + i) * L_WORDS;
#pragma unroll
  for (int j = 0; j < 8; ++j)
    rr[j] = rp + (size_t)(bn0 + tc + 16 * j) * L_WORDS;

  uint32_t acc[4][8] = {};

#pragma unroll 4
  for (int w2 = 0; w2 < L_WORDS / 2; ++w2) {
    ulonglong2 xv[4], rv[8];
#pragma unroll
    for (int i = 0; i < 4; ++i)
      xv[i] = *reinterpret_cast<const ulonglong2*>(xr[i] + w2 * 2);
#pragma unroll
    for (int j = 0; j < 8; ++j)
      rv[j] = *reinterpret_cast<const ulonglong2*>(rr[j] + w2 * 2);
#pragma unroll
    for (int i = 0; i < 4; ++i)
#pragma unroll
      for (int j = 0; j < 8; ++j)
        acc[i][j] += (uint32_t)__popcll(xv[i].x ^ rv[j].x)
                   + (uint32_t)__popcll(xv[i].y ^ rv[j].y);
  }

  // out = (hamming - L/2) / (0.5*sqrt(L)); exact-integer hamming.
  const float inv_std = 0.04419417382415922f;  // 1 / (0.5*sqrt(2048))
#pragma unroll
  for (int i = 0; i < 4; ++i) {
    const int b = bm0 + tr * 4 + i;
#pragma unroll
    for (int j = 0; j < 8; ++j) {
      const int d = bn0 + tc + 16 * j;
      out[(size_t)b * D_ROWS + d] = ((float)acc[i][j] - 1024.0f) * inv_std;
    }
  }
}

extern "C" void kernel_launch(void* const* d_in, const int* in_sizes, int n_in,
                              void* d_out, int out_size, void* d_ws, size_t ws_size,
                              hipStream_t stream) {
  const int*   x = (const int*)d_in[0];     // (4096, 2048) int32
  const float* r = (const float*)d_in[1];   // (1024, 2048) float32
  float*     out = (float*)d_out;           // (4096, 1024) float32

  uint64_t* xp = (uint64_t*)d_ws;                               // 1 MiB
  uint64_t* rp = xp + (size_t)B_ROWS * L_WORDS;                 // +256 KiB

  const int groups_x = B_ROWS * L_LEN / 256;                    // 32768
  const int groups_r = D_ROWS * L_LEN / 256;                    // 8192
  const int groups_total = groups_x + groups_r;                 // 40960

  pack_bits_kernel<<<2048, 256, 0, stream>>>(x, r, xp, rp, groups_x, groups_total);

  dim3 grid(B_ROWS / BM, D_ROWS / BN);  // (64, 8) = 512 blocks
  hamming_kernel<<<grid, 256, 0, stream>>>(xp, rp, out);
}

// Round 6
// 38.025 us; speedup vs baseline: 1.4528x; 1.4528x over previous
//
#include <hip/hip_runtime.h>
#include <stdint.h>

// Problem constants: x (4096, 2048) int32 {0,1}, references (1024, 2048)
// float32 {0,1}, out (4096, 1024) float32.
constexpr int B_ROWS  = 4096;
constexpr int D_ROWS  = 1024;
constexpr int L_LEN   = 2048;
constexpr int L_WORDS = L_LEN / 64;     // 32 uint64 per row
constexpr int W2      = L_WORDS / 2;    // 16 ulonglong2 per row

// ---------------------------------------------------------------------------
// Kernel 1: bit-pack both inputs into TRANSPOSED pair-major layout:
//   xp2[p][b] = {word 2p, word 2p+1} of x-row b   (p = 0..15, b = 0..4095)
//   rp2[p][d] = {word 2p, word 2p+1} of ref-row d
// Word w of row b = __ballot over elements b*2048 + (w>>2)*256 + lane*4 + (w&3).
// Same per-word element permutation for x and refs -> popcount(xor) summed
// over matched words is the exact Hamming distance.
// Reads stay fully coalesced (16B/lane); stores are 2 x 16B scatters from
// lane 0 only (1.25 MiB total -- negligible).
// ---------------------------------------------------------------------------
__global__ __launch_bounds__(256) void pack_bits_kernel(
    const int* __restrict__ x, const float* __restrict__ r,
    ulonglong2* __restrict__ xp2, ulonglong2* __restrict__ rp2,
    int groups_x, int groups_total)
{
  const int lane   = threadIdx.x & 63;
  const int wave   = (int)((blockIdx.x * blockDim.x + threadIdx.x) >> 6);
  const int nwaves = (int)((gridDim.x * blockDim.x) >> 6);

  for (int g = wave; g < groups_total; g += nwaves) {   // g is wave-uniform
    if (g < groups_x) {
      const int4 v = *reinterpret_cast<const int4*>(x + (size_t)g * 256 + lane * 4);
      uint64_t m0 = __ballot(v.x != 0);
      uint64_t m1 = __ballot(v.y != 0);
      uint64_t m2 = __ballot(v.z != 0);
      uint64_t m3 = __ballot(v.w != 0);
      if (lane == 0) {
        const int row = g >> 3;            // x-row
        const int p   = (g & 7) * 2;       // pair index of words (g&7)*4 ..+3
        ulonglong2 a; a.x = m0; a.y = m1;
        ulonglong2 b; b.x = m2; b.y = m3;
        xp2[(size_t)p       * B_ROWS + row] = a;
        xp2[(size_t)(p + 1) * B_ROWS + row] = b;
      }
    } else {
      const int gr = g - groups_x;
      const float4 v = *reinterpret_cast<const float4*>(r + (size_t)gr * 256 + lane * 4);
      uint64_t m0 = __ballot(v.x != 0.0f);
      uint64_t m1 = __ballot(v.y != 0.0f);
      uint64_t m2 = __ballot(v.z != 0.0f);
      uint64_t m3 = __ballot(v.w != 0.0f);
      if (lane == 0) {
        const int row = gr >> 3;
        const int p   = (gr & 7) * 2;
        ulonglong2 a; a.x = m0; a.y = m1;
        ulonglong2 b; b.x = m2; b.y = m3;
        rp2[(size_t)p       * D_ROWS + row] = a;
        rp2[(size_t)(p + 1) * D_ROWS + row] = b;
      }
    }
  }
}

// ---------------------------------------------------------------------------
// Kernel 2 v4: no LDS, transposed operands, 64(b) x 64(d) tile -> 1024 blocks
// = 4 blocks/CU = 16 waves/CU (vs 8 before). 256 threads = 16tc x 16tr,
// thread tile 4(b) x 4(d), acc[4][4].
// Global loads per w2 step (all L1/L2-served, operands = 1.25 MiB total):
//   rv[j]: lanes tc=0..15 read 16 consecutive ulonglong2 -> 256 B contiguous
//          (4 lines/instr; tr-groups broadcast)            [was 16 lines!]
//   xv[i]: 4 distinct addresses within 128 B (broadcast)  -> 1-2 lines/instr
// VALU floor: 2 instr / 32 bits -> 6.8 us chip-wide; VMEM issue ~2 us.
// ---------------------------------------------------------------------------
constexpr int BM = 64;
constexpr int BN = 64;

__global__ __launch_bounds__(256) void hamming_kernel(
    const ulonglong2* __restrict__ xp2, const ulonglong2* __restrict__ rp2,
    float* __restrict__ out)
{
  const int t   = threadIdx.x;
  const int bm0 = blockIdx.x * BM;
  const int bn0 = blockIdx.y * BN;
  const int tc  = t & 15;   // d-col group
  const int tr  = t >> 4;   // b-row group

  const ulonglong2* xptr = xp2 + bm0 + tr * 4;  // +B_ROWS per w2 step
  const ulonglong2* rptr = rp2 + bn0 + tc;      // +D_ROWS per w2 step

  uint32_t acc[4][4] = {};

#pragma unroll 4
  for (int w2 = 0; w2 < W2; ++w2) {
    ulonglong2 xv[4], rv[4];
#pragma unroll
    for (int i = 0; i < 4; ++i) xv[i] = xptr[i];
#pragma unroll
    for (int j = 0; j < 4; ++j) rv[j] = rptr[16 * j];
#pragma unroll
    for (int i = 0; i < 4; ++i)
#pragma unroll
      for (int j = 0; j < 4; ++j)
        acc[i][j] += (uint32_t)__popcll(xv[i].x ^ rv[j].x)
                   + (uint32_t)__popcll(xv[i].y ^ rv[j].y);
    xptr += B_ROWS;
    rptr += D_ROWS;
  }

  // out = (hamming - L/2) / (0.5*sqrt(L)); exact-integer hamming.
  const float inv_std = 0.04419417382415922f;  // 1 / (0.5*sqrt(2048))
#pragma unroll
  for (int i = 0; i < 4; ++i) {
    const int b = bm0 + tr * 4 + i;
#pragma unroll
    for (int j = 0; j < 4; ++j) {
      const int d = bn0 + tc + 16 * j;
      out[(size_t)b * D_ROWS + d] = ((float)acc[i][j] - 1024.0f) * inv_std;
    }
  }
}

extern "C" void kernel_launch(void* const* d_in, const int* in_sizes, int n_in,
                              void* d_out, int out_size, void* d_ws, size_t ws_size,
                              hipStream_t stream) {
  const int*   x = (const int*)d_in[0];     // (4096, 2048) int32
  const float* r = (const float*)d_in[1];   // (1024, 2048) float32
  float*     out = (float*)d_out;           // (4096, 1024) float32

  ulonglong2* xp2 = (ulonglong2*)d_ws;                       // 1 MiB
  ulonglong2* rp2 = xp2 + (size_t)W2 * B_ROWS;               // +256 KiB

  const int groups_x = B_ROWS * L_LEN / 256;                 // 32768
  const int groups_r = D_ROWS * L_LEN / 256;                 // 8192
  const int groups_total = groups_x + groups_r;              // 40960

  pack_bits_kernel<<<2048, 256, 0, stream>>>(x, r, xp2, rp2, groups_x, groups_total);

  dim3 grid(B_ROWS / BM, D_ROWS / BN);  // (64, 16) = 1024 blocks
  hamming_kernel<<<grid, 256, 0, stream>>>(xp2, rp2, out);
}

// Round 7
// 36.305 us; speedup vs baseline: 1.5217x; 1.0474x over previous
//
#include <hip/hip_runtime.h>
#include <stdint.h>

// Problem constants: x (4096, 2048) int32 {0,1}, references (1024, 2048)
// float32 {0,1}, out (4096, 1024) float32.
constexpr int B_ROWS  = 4096;
constexpr int D_ROWS  = 1024;
constexpr int L_LEN   = 2048;
constexpr int L_WORDS = L_LEN / 64;     // 32 uint64 per row
constexpr int W2      = L_WORDS / 2;    // 16 ulonglong2 per row

// ---------------------------------------------------------------------------
// Kernel 1 (UNCHANGED from R6 — control): bit-pack into TRANSPOSED pair-major
// layout: xp2[p][b], rp2[p][d] (p = word-pair 0..15). Same per-word element
// permutation for x and refs -> popcount(xor) is the exact Hamming distance.
// ---------------------------------------------------------------------------
__global__ __launch_bounds__(256) void pack_bits_kernel(
    const int* __restrict__ x, const float* __restrict__ r,
    ulonglong2* __restrict__ xp2, ulonglong2* __restrict__ rp2,
    int groups_x, int groups_total)
{
  const int lane   = threadIdx.x & 63;
  const int wave   = (int)((blockIdx.x * blockDim.x + threadIdx.x) >> 6);
  const int nwaves = (int)((gridDim.x * blockDim.x) >> 6);

  for (int g = wave; g < groups_total; g += nwaves) {   // g is wave-uniform
    if (g < groups_x) {
      const int4 v = *reinterpret_cast<const int4*>(x + (size_t)g * 256 + lane * 4);
      uint64_t m0 = __ballot(v.x != 0);
      uint64_t m1 = __ballot(v.y != 0);
      uint64_t m2 = __ballot(v.z != 0);
      uint64_t m3 = __ballot(v.w != 0);
      if (lane == 0) {
        const int row = g >> 3;
        const int p   = (g & 7) * 2;
        ulonglong2 a; a.x = m0; a.y = m1;
        ulonglong2 b; b.x = m2; b.y = m3;
        xp2[(size_t)p       * B_ROWS + row] = a;
        xp2[(size_t)(p + 1) * B_ROWS + row] = b;
      }
    } else {
      const int gr = g - groups_x;
      const float4 v = *reinterpret_cast<const float4*>(r + (size_t)gr * 256 + lane * 4);
      uint64_t m0 = __ballot(v.x != 0.0f);
      uint64_t m1 = __ballot(v.y != 0.0f);
      uint64_t m2 = __ballot(v.z != 0.0f);
      uint64_t m3 = __ballot(v.w != 0.0f);
      if (lane == 0) {
        const int row = gr >> 3;
        const int p   = (gr & 7) * 2;
        ulonglong2 a; a.x = m0; a.y = m1;
        ulonglong2 b; b.x = m2; b.y = m3;
        rp2[(size_t)p       * D_ROWS + row] = a;
        rp2[(size_t)(p + 1) * D_ROWS + row] = b;
      }
    }
  }
}

// ---------------------------------------------------------------------------
// Kernel 2 v5: scalar/vector pipe split, no LDS.
// Wave layout: each wave owns 8 consecutive b-rows and 64 consecutive d-cols
// (lane = d-col). Per w2 step:
//   x: 8 row-pairs at wave-UNIFORM consecutive addresses (128 B) -> scalar
//      cache path (s_load_dwordx16 x2), zero vector-memory cost
//   r: lane d0+lane reads 1 ulonglong2 -> 64 lanes = 1 KB contiguous, ONE
//      perfectly-coalesced global_load_dwordx4 (16 B/lane sweet spot)
// VMEM instrs: 16/wave (was 128) x 8192 waves = 131K total (4x fewer, ideal
// pattern). Occupancy: 524288 threads = 8192 waves = 8 waves/SIMD; ~40-70
// VGPR, no barrier. v_bcnt's accumulate operand absorbs the adds:
// 8 VALU per row-pair -> ~1100 VALU instr/wave -> ~7.5 us chip-wide floor.
// ---------------------------------------------------------------------------
__global__ __launch_bounds__(256, 6) void hamming_kernel(
    const ulonglong2* __restrict__ xp2, const ulonglong2* __restrict__ rp2,
    float* __restrict__ out)
{
  const int lane = threadIdx.x & 63;
  const int wv   = __builtin_amdgcn_readfirstlane(threadIdx.x >> 6);
  const int b0   = blockIdx.x * 32 + wv * 8;   // 4 waves x 8 rows per block
  const int d    = blockIdx.y * 64 + lane;     // 64 d-cols per block

  const ulonglong2* __restrict__ xrow = xp2 + b0;  // wave-uniform; +B_ROWS/step
  const ulonglong2* __restrict__ rrow = rp2 + d;   // per-lane;     +D_ROWS/step

  uint32_t acc[8] = {};

#pragma unroll 2
  for (int w2 = 0; w2 < W2; ++w2) {
    const ulonglong2 rv = *rrow;                 // coalesced 1 KB / wave
    ulonglong2 xv[8];
#pragma unroll
    for (int i = 0; i < 8; ++i) xv[i] = xrow[i]; // uniform 128 B -> s_load
#pragma unroll
    for (int i = 0; i < 8; ++i)
      acc[i] += (uint32_t)__popcll(xv[i].x ^ rv.x)
              + (uint32_t)__popcll(xv[i].y ^ rv.y);
    xrow += B_ROWS;
    rrow += D_ROWS;
  }

  // out = (hamming - L/2) / (0.5*sqrt(L)); exact-integer hamming.
  const float inv_std = 0.04419417382415922f;  // 1 / (0.5*sqrt(2048))
#pragma unroll
  for (int i = 0; i < 8; ++i)
    out[(size_t)(b0 + i) * D_ROWS + d] = ((float)acc[i] - 1024.0f) * inv_std;
}

extern "C" void kernel_launch(void* const* d_in, const int* in_sizes, int n_in,
                              void* d_out, int out_size, void* d_ws, size_t ws_size,
                              hipStream_t stream) {
  const int*   x = (const int*)d_in[0];     // (4096, 2048) int32
  const float* r = (const float*)d_in[1];   // (1024, 2048) float32
  float*     out = (float*)d_out;           // (4096, 1024) float32

  ulonglong2* xp2 = (ulonglong2*)d_ws;                       // 1 MiB
  ulonglong2* rp2 = xp2 + (size_t)W2 * B_ROWS;               // +256 KiB

  const int groups_x = B_ROWS * L_LEN / 256;                 // 32768
  const int groups_r = D_ROWS * L_LEN / 256;                 // 8192
  const int groups_total = groups_x + groups_r;              // 40960

  pack_bits_kernel<<<2048, 256, 0, stream>>>(x, r, xp2, rp2, groups_x, groups_total);

  dim3 grid(B_ROWS / 32, D_ROWS / 64);  // (128, 16) = 2048 blocks, 8/CU
  hamming_kernel<<<grid, 256, 0, stream>>>(xp2, rp2, out);
}

// Round 8
// 30.000 us; speedup vs baseline: 1.8415x; 1.2101x over previous
//
#include <hip/hip_runtime.h>
#include <stdint.h>

// Problem: x (4096,2048) int32 {0,1}; references (1024,2048) f32 {0,1};
// out (4096,1024) f32 = (hamming - 1024) / (0.5*sqrt(2048)).
// Identity: with s=1-2x, t=1-2r in {+-1}, hamming = (2048 - s.t)/2, so
//   out[b,d] = -(inv_std/2) * dot_pm1(b,d)     (exact integer dot)
constexpr int B_ROWS = 4096;
constexpr int D_ROWS = 1024;
constexpr int L_LEN  = 2048;

using int32x4 = __attribute__((ext_vector_type(4))) int;

// ---------------------------------------------------------------------------
// Kernel 1: convert both inputs to +-1 int8 (0 -> 0x01, 1 -> 0xFF).
// Reads 16 B/lane coalesced, writes 4 B/lane coalesced. ~50 MB traffic.
// ---------------------------------------------------------------------------
__global__ __launch_bounds__(256) void convert_kernel(
    const int* __restrict__ x, const float* __restrict__ r,
    uint32_t* __restrict__ xq, uint32_t* __restrict__ rq,
    int groups_x, int groups_total)
{
  const int tid = blockIdx.x * blockDim.x + threadIdx.x;
  const int nth = gridDim.x * blockDim.x;
  for (int g = tid; g < groups_total; g += nth) {
    if (g < groups_x) {
      const int4 v = *reinterpret_cast<const int4*>(x + (size_t)g * 4);
      const uint32_t b0 = v.x ? 0xFFu : 0x01u;
      const uint32_t b1 = v.y ? 0xFFu : 0x01u;
      const uint32_t b2 = v.z ? 0xFFu : 0x01u;
      const uint32_t b3 = v.w ? 0xFFu : 0x01u;
      xq[g] = b0 | (b1 << 8) | (b2 << 16) | (b3 << 24);
    } else {
      const int gr = g - groups_x;
      const float4 v = *reinterpret_cast<const float4*>(r + (size_t)gr * 4);
      const uint32_t b0 = (v.x != 0.0f) ? 0xFFu : 0x01u;
      const uint32_t b1 = (v.y != 0.0f) ? 0xFFu : 0x01u;
      const uint32_t b2 = (v.z != 0.0f) ? 0xFFu : 0x01u;
      const uint32_t b3 = (v.w != 0.0f) ? 0xFFu : 0x01u;
      rq[gr] = b0 | (b1 << 8) | (b2 << 16) | (b3 << 24);
    }
  }
}

// ---------------------------------------------------------------------------
// Kernel 2: i8 GEMM (m97 structure). C[b,d] = sum_k A[b,k]*B[d,k], both
// row-major i8 ("B^T input" form). Tile BM=128 x BN=64, BK=128, 256 threads
// (4 waves; wave grid 2x2, wave tile 64x32). mfma_i32_16x16x64_i8, symmetric
// fragment layout: lane reads 16 contiguous K-bytes of row (lane&15), k-chunk
// (lane>>4)*16 — the layout verified by the m97 bf16 ladder, scaled 2x K.
// LDS XOR-swizzle (T2, rule #21): global_load_lds writes LINEAR dest while
// the SOURCE column is pre-swizzled (col ^ ((row&7)<<4)); frag reads apply
// the same XOR -> ds_read_b128 lands ~2-way (free) instead of 16-way.
// K-steps: 2048/128 = 16; per wave per step: 6 global_load_lds_dwordx4,
// 12 ds_read_b128, 16 MFMA.
// ---------------------------------------------------------------------------
constexpr int BM = 128;
constexpr int BN = 64;
constexpr int BK = 128;
constexpr int KSTEPS = L_LEN / BK;   // 16

typedef __attribute__((address_space(3))) void       as3_void;
typedef const __attribute__((address_space(1))) void as1_cvoid;

__device__ __forceinline__ void gload_lds16(const void* g, void* l) {
  __builtin_amdgcn_global_load_lds((as1_cvoid*)g, (as3_void*)l, 16, 0, 0);
}

__global__ __launch_bounds__(256) void gemm_i8_kernel(
    const char* __restrict__ Aq, const char* __restrict__ Bq,
    float* __restrict__ out)
{
  __shared__ __align__(16) char A_lds[BM * BK];   // 16 KB
  __shared__ __align__(16) char B_lds[BN * BK];   //  8 KB

  const int t    = threadIdx.x;
  const int lane = t & 63;
  const int w    = t >> 6;          // wave 0..3
  const int wr   = w >> 1;          // wave row (m)
  const int wc   = w & 1;           // wave col (n)
  const int bm   = blockIdx.x * BM;
  const int bn   = blockIdx.y * BN;

  const int l8  = lane >> 3;        // row within 8-row staging group
  const int c16 = lane & 7;         // 16B slot within 128B row

  int32x4 acc[4][2] = {};           // 32 VGPR accumulator, static-indexed

  for (int ks = 0; ks < KSTEPS; ++ks) {
    const int k0 = ks * BK;

    // Stage A-tile: 4 wave-calls x 1 KB (8 rows of 128 B each).
#pragma unroll
    for (int c = 0; c < 4; ++c) {
      const int rb = c * 32 + w * 8;          // wave-uniform row base
      const int r  = rb + l8;                 // per-lane row
      const char* g = Aq + (size_t)(bm + r) * L_LEN + k0 + ((c16 ^ (r & 7)) * 16);
      gload_lds16(g, A_lds + rb * BK);        // linear dest, pre-swz source
    }
    // Stage B-tile: 2 wave-calls.
#pragma unroll
    for (int c = 0; c < 2; ++c) {
      const int rb = c * 32 + w * 8;
      const int r  = rb + l8;
      const char* g = Bq + (size_t)(bn + r) * L_LEN + k0 + ((c16 ^ (r & 7)) * 16);
      gload_lds16(g, B_lds + rb * BK);
    }
    __syncthreads();   // compiler emits vmcnt(0)+lgkmcnt(0) drain

    // Fragment reads (swizzled) + MFMA.
    int32x4 a[4][2], b[2][2];
#pragma unroll
    for (int kk = 0; kk < 2; ++kk) {
      const int kcol = kk * 64 + (lane >> 4) * 16;
#pragma unroll
      for (int f = 0; f < 4; ++f) {
        const int row = wr * 64 + f * 16 + (lane & 15);
        a[f][kk] = *reinterpret_cast<const int32x4*>(
            A_lds + row * BK + (kcol ^ ((row & 7) << 4)));
      }
#pragma unroll
      for (int gg = 0; gg < 2; ++gg) {
        const int row = wc * 32 + gg * 16 + (lane & 15);
        b[gg][kk] = *reinterpret_cast<const int32x4*>(
            B_lds + row * BK + (kcol ^ ((row & 7) << 4)));
      }
    }
#pragma unroll
    for (int f = 0; f < 4; ++f)
#pragma unroll
      for (int gg = 0; gg < 2; ++gg)
#pragma unroll
        for (int kk = 0; kk < 2; ++kk)
          acc[f][gg] = __builtin_amdgcn_mfma_i32_16x16x64_i8(
              a[f][kk], b[gg][kk], acc[f][gg], 0, 0, 0);
    __syncthreads();   // protect LDS before next stage (single-buffered)
  }

  // Epilogue: C/D layout (verified, dtype-independent): col = lane&15,
  // row = (lane>>4)*4 + reg.  out = dot * (-inv_std/2).
  const float scale = -0.5f * 0.04419417382415922f;
#pragma unroll
  for (int f = 0; f < 4; ++f) {
    const int brow = bm + wr * 64 + f * 16 + (lane >> 4) * 4;
#pragma unroll
    for (int gg = 0; gg < 2; ++gg) {
      const int d = bn + wc * 32 + gg * 16 + (lane & 15);
#pragma unroll
      for (int reg = 0; reg < 4; ++reg)
        out[(size_t)(brow + reg) * D_ROWS + d] = (float)acc[f][gg][reg] * scale;
    }
  }
}

extern "C" void kernel_launch(void* const* d_in, const int* in_sizes, int n_in,
                              void* d_out, int out_size, void* d_ws, size_t ws_size,
                              hipStream_t stream) {
  const int*   x = (const int*)d_in[0];     // (4096, 2048) int32
  const float* r = (const float*)d_in[1];   // (1024, 2048) float32
  float*     out = (float*)d_out;           // (4096, 1024) float32

  char* Aq = (char*)d_ws;                               // 8 MiB  (4096x2048 i8)
  char* Bq = Aq + (size_t)B_ROWS * L_LEN;               // 2 MiB  (1024x2048 i8)

  const int groups_x = B_ROWS * L_LEN / 4;              // 2097152
  const int groups_r = D_ROWS * L_LEN / 4;              // 524288
  const int groups_total = groups_x + groups_r;

  convert_kernel<<<2048, 256, 0, stream>>>(
      x, r, (uint32_t*)Aq, (uint32_t*)Bq, groups_x, groups_total);

  dim3 grid(B_ROWS / BM, D_ROWS / BN);  // (32, 16) = 512 blocks, 2/CU
  gemm_i8_kernel<<<grid, 256, 0, stream>>>(Aq, Bq, out);
}